// Round 10
// baseline (1011.937 us; speedup 1.0000x reference)
//
#include <hip/hip_runtime.h>
#include <hip/hip_cooperative_groups.h>
#include <stdint.h>

namespace cg = cooperative_groups;

#define XH   256
#define NCLS 104

typedef _Float16 half2v __attribute__((ext_vector_type(2)));
typedef _Float16 half4v __attribute__((ext_vector_type(4)));
typedef _Float16 half8v __attribute__((ext_vector_type(8)));
typedef __attribute__((ext_vector_type(4))) float floatx4;

__device__ __forceinline__ void gll16(const void* g, void* l) {
    __builtin_amdgcn_global_load_lds(
        (const __attribute__((address_space(1))) unsigned*)g,
        (__attribute__((address_space(3))) unsigned*)l, 16, 0, 0);
}
__device__ __forceinline__ float fdot2f(half2v a, half2v b, float c) {
#if __has_builtin(__builtin_amdgcn_fdot2)
    return __builtin_amdgcn_fdot2(a, b, c, false);
#else
    return c + (float)a[0] * (float)b[0] + (float)a[1] * (float)b[1];
#endif
}
// 16B-granule XOR swizzle within 64B groups: 2-way-max LDS bank aliasing
__device__ __forceinline__ int MF(int x) { return (x + (x >> 2)) & 3; }

// W16 sections (element offsets, VQ = vocab*256):
//   0:Yl   VQ:Yr   2VQ:Ym=(Yl+Yr)/2   3VQ:Yt(+b_conv)   4VQ:embf

// ===========================================================================
// Phase 0: Btw transpose + edge descriptors + CSR row_start (grid-stride)
// ===========================================================================
__device__ __forceinline__ void phase0_dev(
        const int* __restrict__ nty, const int* __restrict__ edge_src,
        const int* __restrict__ edge_dst, const float* __restrict__ alpha,
        const float* __restrict__ Wl, const float* __restrict__ Wr,
        const float* __restrict__ Wt, _Float16* __restrict__ Btw,
        int2* __restrict__ epk, int* __restrict__ row_start, int VQ, int E) {
    const int total0 = 3 * XH * XH + E;
    for (int idx = blockIdx.x * 1024 + threadIdx.x; idx < total0;
         idx += gridDim.x * 1024) {
        if (idx < 3 * XH * XH) {
            int n = idx >> 8, k = idx & 255;
            int m, c;
            if (n < 512) { m = n & 1; c = n >> 1; }
            else         { m = 2;     c = n - 512; }
            const float* W = (m == 0) ? Wl : (m == 1) ? Wr : Wt;
            Btw[idx] = (_Float16)W[k * XH + c];
        } else {
            int e = idx - 3 * XH * XH;
            int s  = edge_src[e];
            float a = alpha[e];
            int ts = nty[s];
            int x;
            half2v w;
            if      (a == 0.0f) { x = ts * 256;          w = half2v{1.0f16, 0.0f16}; }
            else if (a == 1.0f) { x = VQ + ts * 256;     w = half2v{1.0f16, 0.0f16}; }
            else if (a == 0.5f) { x = 2 * VQ + ts * 256; w = half2v{1.0f16, 0.0f16}; }
            else { x = (ts * 256) | 1; w = half2v{(_Float16)(1.f - a), (_Float16)a}; }
            int2 p;
            p.x = x;
            p.y = __builtin_bit_cast(int, w);
            epk[e] = p;
            int d = edge_dst[e];
            if (e == 0 || edge_dst[e - 1] != d) row_start[d] = e;
        }
    }
}

// ===========================================================================
// Phase 1: GEMM [Yl|Yr|Ym|Yt|embf] = f16(emb) @ Btw^T.  32-row tiles
// (grid-stride), two 384-col passes, Bb 24 KB + Ab 16 KB = 40 KB LDS.
// 16 waves: mw = wv&1 (16-row strip), nq = wv>>1 (48-col group).
// ===========================================================================
__device__ __forceinline__ void phase1_dev(
        char* smem, const float* __restrict__ emb,
        const _Float16* __restrict__ Btw, const float* __restrict__ b_conv,
        _Float16* __restrict__ W16, int vocab, int VQ) {
    _Float16* Ab = (_Float16*)smem;              // 16 KB [32 rows][256 k swizzled]
    _Float16* Bb = (_Float16*)(smem + 16384);    // 24 KB [384 rows][32 k] / epilogue

    const int tid  = threadIdx.x;
    const int lane = tid & 63;
    const int wv   = tid >> 6;        // 0..15
    const int quad = lane >> 4;
    const int l15  = lane & 15;
    const int mw   = wv & 1;
    const int nq   = wv >> 1;         // 0..7
    const int Mt   = vocab / 32;

    for (int tile = blockIdx.x; tile < Mt; tile += gridDim.x) {
        const int m0 = tile * 32;
        // ---- A-stage: 32 rows x 256 k fp32 -> f16 LDS (+ embf section)
        {
            int row = tid >> 5;          // 0..31
            int cg8 = tid & 31;          // 16B granule (8 f16)
            const float* ga = &emb[(size_t)(m0 + row) * XH + cg8 * 8];
            floatx4 f0 = *(const floatx4*)ga;
            floatx4 f1 = *(const floatx4*)(ga + 4);
            half8v h;
            #pragma unroll
            for (int i = 0; i < 4; i++) { h[i] = (_Float16)f0[i]; h[4 + i] = (_Float16)f1[i]; }
            *(half8v*)&Ab[row * 256 + (cg8 >> 2) * 32 + ((cg8 & 3) ^ MF(row & 15)) * 8] = h;
            *(half8v*)&W16[(size_t)4 * VQ + (size_t)(m0 + row) * 256 + cg8 * 8] = h;
        }

        auto stageB = [&](int np, int kc) {   // 384 rows x 64 B, 24 groups of 1 KB
            #pragma unroll
            for (int i = 0; i < 2; i++) {
                int grp = wv + i * 16;
                if (grp < 24) {
                    int row = grp * 16 + (lane >> 2);          // local 0..383
                    int bd  = (lane & 3) ^ MF(row & 15);
                    gll16((const char*)Btw + (size_t)(np * 384 + row) * 512 + kc * 64 + bd * 16,
                          (char*)Bb + grp * 1024);
                }
            }
        };

        for (int np = 0; np < 2; np++) {
            stageB(np, 0);
            floatx4 acc[3];
            #pragma unroll
            for (int i = 0; i < 3; i++) acc[i] = floatx4{0.f, 0.f, 0.f, 0.f};

            for (int kc = 0; kc < 8; kc++) {
                __syncthreads();             // Bb[kc] (and Ab first time) ready
                half8v af[3], bf;
                #pragma unroll
                for (int nt = 0; nt < 3; nt++) {
                    int row = nq * 48 + nt * 16 + l15;
                    af[nt] = *(const half8v*)&Bb[row * 32 + ((quad ^ MF(l15)) * 8)];
                }
                {
                    int row = mw * 16 + l15;
                    bf = *(const half8v*)&Ab[row * 256 + kc * 32 + ((quad ^ MF(l15)) * 8)];
                }
                __syncthreads();             // all reads done; Bb reusable
                if (kc < 7) stageB(np, kc + 1);
                #pragma unroll
                for (int nt = 0; nt < 3; nt++)
                    acc[nt] = __builtin_amdgcn_mfma_f32_16x16x32_f16(af[nt], bf, acc[nt], 0, 0, 0);
            }

            // ---- epilogue: acc -> Bb as [32 m][384 nloc] (8B-granule swizzle)
            {
                int m = mw * 16 + l15;
                #pragma unroll
                for (int nt = 0; nt < 3; nt++) {
                    int n0 = nq * 48 + nt * 16 + quad * 4;   // local n
                    half4v hv;
                    #pragma unroll
                    for (int r = 0; r < 4; r++) hv[r] = (_Float16)acc[nt][r];
                    int gs = (n0 >> 2) ^ (m & 7);
                    *(half4v*)((char*)Bb + (size_t)m * 768 + gs * 8) = hv;
                }
            }
            __syncthreads();

            // ---- coalesced section stores (1536 units of 8 n each)
            #pragma unroll
            for (int it = 0; it < 2; it++) {
                int u = it * 1024 + tid;
                if (u < 1536) {
                    int m = u / 48, g = u % 48;
                    int nloc = g * 8;
                    int n0 = np * 384 + nloc;
                    int q0 = ((nloc >> 2) + 0) ^ (m & 7);
                    int q1 = ((nloc >> 2) + 1) ^ (m & 7);
                    half4v v0 = *(const half4v*)((const char*)Bb + (size_t)m * 768 + q0 * 8);
                    half4v v1 = *(const half4v*)((const char*)Bb + (size_t)m * 768 + q1 * 8);
                    if (n0 < 512) {
                        // interleaved pairs: n=2c+b (b=0:left,1:right)
                        int c0 = n0 >> 1;
                        float l0 = (float)v0[0], r0 = (float)v0[1];
                        float l1 = (float)v0[2], r1 = (float)v0[3];
                        float l2 = (float)v1[0], r2 = (float)v1[1];
                        float l3 = (float)v1[2], r3 = (float)v1[3];
                        half4v yl = { (_Float16)l0, (_Float16)l1, (_Float16)l2, (_Float16)l3 };
                        half4v yr = { (_Float16)r0, (_Float16)r1, (_Float16)r2, (_Float16)r3 };
                        half4v ym = { (_Float16)(0.5f * (l0 + r0)), (_Float16)(0.5f * (l1 + r1)),
                                      (_Float16)(0.5f * (l2 + r2)), (_Float16)(0.5f * (l3 + r3)) };
                        size_t ro = (size_t)(m0 + m) * 256 + c0;
                        *(half4v*)&W16[ro]          = yl;
                        *(half4v*)&W16[VQ + ro]     = yr;
                        *(half4v*)&W16[2 * VQ + ro] = ym;
                    } else {
                        int ch = n0 - 512;
                        floatx4 b0 = *(const floatx4*)&b_conv[ch];
                        floatx4 b1 = *(const floatx4*)&b_conv[ch + 4];
                        half8v o;
                        #pragma unroll
                        for (int i = 0; i < 4; i++) {
                            o[i]     = (_Float16)((float)v0[i] + b0[i]);
                            o[4 + i] = (_Float16)((float)v1[i] + b1[i]);
                        }
                        *(half8v*)&W16[(size_t)3 * VQ + (size_t)(m0 + m) * 256 + ch] = o;
                    }
                }
            }
            __syncthreads();                 // Bb free for next pass / tile
        }
    }
}

// ===========================================================================
// Phase 2: per-graph fused conv-gather + attention pool + classifier
// (byte-identical to round-7 k_graph body; 28 VGPR proven)
// ===========================================================================
__device__ __forceinline__ void phase2_dev(
        char* smem, const int* __restrict__ nty, const int* __restrict__ cc,
        const _Float16* __restrict__ W16, const int2* __restrict__ epk,
        const int* __restrict__ row_start, const float* __restrict__ gate_w,
        const float* __restrict__ gate_b, const float* __restrict__ cls_w,
        const float* __restrict__ cls_b, float* __restrict__ out,
        int PER, int VQ, int E) {
    float* pw     = (float*)smem;            // 16 KB
    float* dsh    = (float*)(smem + 16384);  // 64 B
    float* pooled = (float*)(smem + 16448);  // 1 KB

    const int g    = blockIdx.x;
    const int tid  = threadIdx.x;
    const int lane = tid & 63;
    const int wv   = tid >> 6;       // 0..15
    const int base = g * PER;

    float gw4[4];
    #pragma unroll
    for (int i = 0; i < 4; i++) gw4[i] = gate_w[4 * lane + i];
    const float gb = gate_b[0];

    float acc4[4] = {0.f, 0.f, 0.f, 0.f};
    float dsum = 0.f;

    int vg = base + wv;
    int c  = cc[vg];
    int tv = nty[vg];
    int rs = (c > 0) ? row_start[vg] : 0;
    half4v yt = *(const half4v*)&W16[(size_t)(c == 0 ? 4 : 3) * VQ + (size_t)tv * 256 + 4 * lane];
    int2 pd0 = epk[rs];

    for (int v = wv; v < PER; v += 16) {
        const bool has = (v + 16 < PER);
        const int vns = has ? vg + 16 : vg;
        int cn  = has ? cc[vns] : 0;
        int tvn = nty[vns];
        int rsn = (has && cn > 0) ? row_start[vns] : 0;
        half4v ytn = *(const half4v*)&W16[(size_t)(cn == 0 ? 4 : 3) * VQ + (size_t)tvn * 256 + 4 * lane];
        int2 pdn = epk[rsn];

        float h4[4];
        if (c == 0) {
            #pragma unroll
            for (int i = 0; i < 4; i++) h4[i] = (float)yt[i];
        } else {
            float s4[4] = {0.f, 0.f, 0.f, 0.f};
            int e = rs;
            const int e1 = rs + c;
            int2 p0 = pd0;
            while (e + 2 <= e1) {
                int2 p1 = epk[e + 1];
                int2 pn = epk[min(e + 2, E - 1)];
                int off0 = p0.x & ~1, d0 = (p0.x & 1) ? VQ : 0;
                int off1 = p1.x & ~1, d1 = (p1.x & 1) ? VQ : 0;
                half4v a0 = *(const half4v*)&W16[(size_t)off0 + 4 * lane];
                half4v b0 = *(const half4v*)&W16[(size_t)(off0 + d0) + 4 * lane];
                half4v a1 = *(const half4v*)&W16[(size_t)off1 + 4 * lane];
                half4v b1 = *(const half4v*)&W16[(size_t)(off1 + d1) + 4 * lane];
                half2v w0 = __builtin_bit_cast(half2v, p0.y);
                half2v w1 = __builtin_bit_cast(half2v, p1.y);
                #pragma unroll
                for (int i = 0; i < 4; i++)
                    s4[i] = fdot2f(half2v{a0[i], b0[i]}, w0, s4[i]);
                #pragma unroll
                for (int i = 0; i < 4; i++)
                    s4[i] = fdot2f(half2v{a1[i], b1[i]}, w1, s4[i]);
                p0 = pn;
                e += 2;
            }
            if (e < e1) {
                int off0 = p0.x & ~1, d0 = (p0.x & 1) ? VQ : 0;
                half4v a0 = *(const half4v*)&W16[(size_t)off0 + 4 * lane];
                half4v b0 = *(const half4v*)&W16[(size_t)(off0 + d0) + 4 * lane];
                half2v w0 = __builtin_bit_cast(half2v, p0.y);
                #pragma unroll
                for (int i = 0; i < 4; i++)
                    s4[i] = fdot2f(half2v{a0[i], b0[i]}, w0, s4[i]);
            }
            #pragma unroll
            for (int i = 0; i < 4; i++)
                h4[i] = fmaxf(s4[i] + (float)yt[i], 0.f);   // bias in Yt
        }

        float sg = h4[0] * gw4[0] + h4[1] * gw4[1] + h4[2] * gw4[2] + h4[3] * gw4[3];
        #pragma unroll
        for (int o = 1; o < 64; o <<= 1) sg += __shfl_xor(sg, o);
        float ew = __expf(sg + gb);
        dsum += ew;
        #pragma unroll
        for (int i = 0; i < 4; i++) acc4[i] += ew * h4[i];

        c = cn; rs = rsn; yt = ytn; pd0 = pdn; vg = vns;
    }

    #pragma unroll
    for (int i = 0; i < 4; i++) pw[wv * XH + 4 * lane + i] = acc4[i];
    if (lane == 0) dsh[wv] = dsum;
    __syncthreads();

    if (tid < XH) {
        float p = 0.f, d = 0.f;
        #pragma unroll
        for (int w = 0; w < 16; w++) p += pw[w * XH + tid];
        #pragma unroll
        for (int w = 0; w < 16; w++) d += dsh[w];
        pooled[tid] = p / d;
    }
    __syncthreads();

    if (tid < NCLS) {
        float o = cls_b[tid];
        #pragma unroll 8
        for (int k = 0; k < XH; k++) o += pooled[k] * cls_w[k * NCLS + tid];
        out[g * NCLS + tid] = o;
    }
}

// ===========================================================================
// Cooperative all-in-one kernel (40 KB LDS, <=64 VGPR target)
// ===========================================================================
__global__ __launch_bounds__(1024, 8)
void k_fused(const int* nty, const int* edge_src, const int* edge_dst,
             const float* alpha, const int* cc, const float* emb,
             const float* Wl, const float* Wr, const float* Wt,
             const float* b_conv, const float* gate_w, const float* gate_b,
             const float* cls_w, const float* cls_b,
             _Float16* W16, _Float16* Btw, int2* epk, int* row_start,
             float* out, int vocab, int E, int PER, int VQ) {
    __shared__ __align__(16) char smem[40960];
    cg::grid_group grid = cg::this_grid();

    phase0_dev(nty, edge_src, edge_dst, alpha, Wl, Wr, Wt, Btw, epk, row_start, VQ, E);
    __threadfence();
    grid.sync();
    __threadfence();
    phase1_dev(smem, emb, Btw, b_conv, W16, vocab, VQ);
    __threadfence();
    grid.sync();
    __threadfence();
    phase2_dev(smem, nty, cc, W16, epk, row_start, gate_w, gate_b, cls_w, cls_b,
               out, PER, VQ, E);
}

// ===========================================================================
// Fallback: same phases as three ordinary kernels
// ===========================================================================
__global__ __launch_bounds__(1024)
void k_p0f(const int* nty, const int* edge_src, const int* edge_dst,
           const float* alpha, const float* Wl, const float* Wr, const float* Wt,
           _Float16* Btw, int2* epk, int* row_start, int VQ, int E) {
    phase0_dev(nty, edge_src, edge_dst, alpha, Wl, Wr, Wt, Btw, epk, row_start, VQ, E);
}

__global__ __launch_bounds__(1024, 4)
void k_p1f(const float* emb, const _Float16* Btw, const float* b_conv,
           _Float16* W16, int vocab, int VQ) {
    __shared__ __align__(16) char smem[40960];
    phase1_dev(smem, emb, Btw, b_conv, W16, vocab, VQ);
}

__global__ __launch_bounds__(1024, 8)
void k_p2f(const int* nty, const int* cc, const _Float16* W16, const int2* epk,
           const int* row_start, const float* gate_w, const float* gate_b,
           const float* cls_w, const float* cls_b, float* out,
           int PER, int VQ, int E) {
    __shared__ __align__(16) char smem[17472];
    phase2_dev(smem, nty, cc, W16, epk, row_start, gate_w, gate_b, cls_w, cls_b,
               out, PER, VQ, E);
}

// ---------------------------------------------------------------------------
extern "C" void kernel_launch(void* const* d_in, const int* in_sizes, int n_in,
                              void* d_out, int out_size, void* d_ws, size_t ws_size,
                              hipStream_t stream) {
    const int*   node_type   = (const int*)d_in[0];
    const int*   edge_src    = (const int*)d_in[1];
    const int*   edge_dst    = (const int*)d_in[2];
    const float* alpha       = (const float*)d_in[3];
    const int*   child_count = (const int*)d_in[4];
    // d_in[5] graph_ids unused: nodes of a graph are contiguous
    const float* emb         = (const float*)d_in[6];
    const float* Wl          = (const float*)d_in[7];
    const float* Wr          = (const float*)d_in[8];
    const float* Wt          = (const float*)d_in[9];
    const float* b_conv      = (const float*)d_in[10];
    const float* gate_w      = (const float*)d_in[11];
    const float* gate_b      = (const float*)d_in[12];
    const float* cls_w       = (const float*)d_in[13];
    const float* cls_b       = (const float*)d_in[14];

    const int N     = in_sizes[0];
    int       E     = in_sizes[1];
    int       vocab = in_sizes[6] / XH;
    const int G     = out_size / NCLS;
    int       PER   = N / G;
    int       VQ    = vocab * 256;

    _Float16* W16 = (_Float16*)d_ws;                          // 5*VQ f16
    _Float16* Btw = W16 + (size_t)5 * VQ;                     // 768*256 f16
    int2*     epk = (int2*)(Btw + 3 * XH * XH);               // E * 8B
    int*      row_start = (int*)(epk + E);                    // N * 4B

    float* outf = (float*)d_out;
    void* args[] = {
        (void*)&node_type, (void*)&edge_src, (void*)&edge_dst, (void*)&alpha,
        (void*)&child_count, (void*)&emb, (void*)&Wl, (void*)&Wr, (void*)&Wt,
        (void*)&b_conv, (void*)&gate_w, (void*)&gate_b, (void*)&cls_w,
        (void*)&cls_b, (void*)&W16, (void*)&Btw, (void*)&epk, (void*)&row_start,
        (void*)&outf, (void*)&vocab, (void*)&E, (void*)&PER, (void*)&VQ,
    };

    hipError_t st = hipLaunchCooperativeKernel((const void*)k_fused, dim3(G),
                                               dim3(1024), args, 0, stream);
    if (st != hipSuccess) {
        (void)hipGetLastError();   // clear sticky error; use ordinary pipeline
        hipLaunchKernelGGL(k_p0f, dim3(G), dim3(1024), 0, stream,
                           node_type, edge_src, edge_dst, alpha, Wl, Wr, Wt,
                           Btw, epk, row_start, VQ, E);
        hipLaunchKernelGGL(k_p1f, dim3(G), dim3(1024), 0, stream,
                           emb, Btw, b_conv, W16, vocab, VQ);
        hipLaunchKernelGGL(k_p2f, dim3(G), dim3(1024), 0, stream,
                           node_type, child_count, W16, epk, row_start,
                           gate_w, gate_b, cls_w, cls_b, outf, PER, VQ, E);
    }
}